// Round 11
// baseline (24.601 us; speedup 1.0000x reference)
//
#include <hip/hip_runtime.h>
#include <math.h>

// B=64, C=3, H=W=256 fixed by the reference problem.
#define BATCH 64
#define CH 3
#define IMH 256
#define IMW 256
#define HW (IMH * IMW)
#define NXCD 8

// 32x64 output tile, ALL 3 channels per block, double-buffered LDS pipeline.
// Row span: |id_|max*31 + ie_max*63 = 24.44+77.28 = 101.7 -> NR <= 104 (+pad).
// Col bound: 31*c + 1 tap + 3 align slack + 1 <= 36.
#define NRMAX 106
#define XW 36
#define XW4 9            // float4 per staged row
#define NQ (NRMAX * XW4) // 954 quads = 15.26 KB per buffer
#define NIT 4            // ceil(954/256)
// LDS = 2 * 954 * 16 B = 30.5 KB -> 5 blocks/CU.

#define AS1 __attribute__((address_space(1)))
#define AS3 __attribute__((address_space(3)))

__device__ __forceinline__ int clampi(int v, int lo, int hi) {
    return min(max(v, lo), hi);
}

__global__ __launch_bounds__(256, 5) void TCR_52536039964687_warp(
    const float* __restrict__ img,
    const float* __restrict__ rnd,
    float* __restrict__ out) {
    __shared__ float4 ldsA[NQ];
    __shared__ float4 ldsB[NQ];

    // 2048 blocks = 64 images x 32 tiles (8 in x, 4 in y of 32x64).
    // XCD-affinity: all 32 tiles of image b land on XCD b%8
    // (assumes HW round-robin xcd = bid % 8; perf-only assumption).
    int w = blockIdx.x;
    int xcd = w & (NXCD - 1);
    unsigned t = (unsigned)w >> 3;   // 0..255 within XCD
    unsigned islot = t >> 5;         // image slot within XCD, 0..7
    int tile = (int)(t & 31u);
    int b = ((int)islot << 3) | xcd; // image index
    int X0 = (tile & 7) << 5;        // tile col origin (32-wide)
    int Y0 = (tile >> 3) << 6;       // tile row origin (64-tall)

    int tid = threadIdx.x;
    int dx = tid & 31;               // output col within tile
    int qy = tid >> 5;               // 0..7 row phase; rows Y0+qy+8k, k<8

    // ---- per-image inverse affine coefficients (simplified; a==0 exactly) ----
    const float r = rnd[b];
    const float ANG  = 0.34906585039886590f;   // deg2rad(20)
    const float ANG2 = 0.69813170079773179f;   // 2*ANG
    const float Wc = (float)IMH;
    const float Hc = (float)IMW;

    float tx  = 12.0f * r - 6.0f;
    float ty  = tx;
    float rho = ANG2 * r - ANG;

    float s = __sinf(rho);
    float c = __cosf(rho);            // 0.9397 <= c <= 1.0
    float cb = 2.f * c * c - 1.f;     // cos(2*rho) >= 0.766
    float sb = 2.f * s * c;           // sin(2*rho)
    float rcb = 1.f / cb;

    float ic  = 0.5f * Wc * (1.f - c) - tx;
    float id_ = -sb * c * rcb;        // |id_| <= 0.7885
    float ie  = c * rcb;              // 1.0 <= ie <= 1.2267
    float P   = 0.5f * (Wc * c - Wc + 2.f * tx);
    float Q   = 0.5f * (Hc * c - Wc * cb + 2.f * ty * cb - Wc * sb + 2.f * tx * sb);
    float if_ = (sb * P - Q) * rcb;
    // sx = fmaf(c, x, ic); sy = fmaf(id_, x, fmaf(ie, y, if_))

    // ---- tile source bounds via corners (same fmaf composition as below;
    //      fma monotone per operand, c>0, ie>0 -> corners bound the tile) ----
    float X0f = (float)X0, X1f = (float)(X0 + 31);
    float Y0f = (float)Y0, Y1f = (float)(Y0 + 63);
    float sxlo = fmaf(c, X0f, ic);
    int lxmin = clampi((int)floorf(sxlo), 0, IMW - 2);
    int axlo = lxmin & ~3;            // 16B-aligned staging origin

    float g0 = fmaf(ie, Y0f, if_);
    float g1 = fmaf(ie, Y1f, if_);    // g1 >= g0
    float syA = fmaf(id_, X0f, g0), syB = fmaf(id_, X1f, g0);
    float syC = fmaf(id_, X0f, g1), syD = fmaf(id_, X1f, g1);
    float symin = fminf(fminf(syA, syB), fminf(syC, syD));
    float symax = fmaxf(fmaxf(syA, syB), fmaxf(syC, syD));
    int rlo = clampi((int)floorf(symin), 0, IMH - 1);
    int rhi = clampi((int)floorf(symax) + 1, 0, IMH - 1);
    int NR = rhi - rlo + 1;           // <= 104 by construction
    int nq = NR * XW4;                // quads actually needed (<= 954)

    const float* ibase = img + (size_t)b * CH * HW;

    // Stage channel ch via async global->LDS (no VGPR transit).
    // LDS layout exactly wave-linear: float offset row*36+4q == 4*e, so dest
    // byte = 16*e = wave-uniform base + lane*16. Source per-lane. Quads
    // clamped to gq=IMW-4 are never sampled (sampled quad base <= 252).
    // row/q/gq are channel-invariant -> compiler CSEs across the 3 STAGEs.
    #define STAGE(ch_, buf_) {                                                \
        const float* cbase = ibase + (ch_) * HW;                              \
        _Pragma("unroll")                                                     \
        for (int it = 0; it < NIT; ++it) {                                    \
            int e = tid + it * 256;                                           \
            if (e < nq) {                                                     \
                unsigned row = (unsigned)e / XW4;                             \
                int q = e - (int)row * XW4;                                   \
                int gq = min(axlo + 4 * q, IMW - 4);                          \
                const float* gp = cbase + (rlo + (int)row) * IMW + gq;        \
                __builtin_amdgcn_global_load_lds((const AS1 void*)gp,         \
                                                 (AS3 void*)&(buf_)[e],       \
                                                 16, 0, 0);                   \
            }                                                                 \
        }                                                                     \
    }

    // ---- issue channel-0 staging first; tap math hides its latency ----
    STAGE(0, ldsA);

    // ---- per-thread x taps (row- and channel-invariant) ----
    float fx = (float)(X0 + dx);
    float sx = fmaf(c, fx, ic);
    float x0f = floorf(sx);
    int x0 = (int)x0f;
    float wx = sx - x0f;
    int lx = clampi(x0, 0, IMW - 2);  // (lx,lx+1) provably inside staged cols
    float wl = (x0 == lx) ? (1.f - wx) : ((x0 == lx - 1) ? wx : 0.f);
    float wh = (x0 == lx) ? wx : ((x0 == lx + 1) ? (1.f - wx) : 0.f);
    int px = lx - axlo;               // 0..34

    // ---- per-thread y taps: 8 rows (Y0+qy+8k), computed ONCE, reused x3 ----
    int   a01[8];                     // lo16 = (r0,px) word addr, hi16 = (r1,px)
    float wy0[8], wy1[8];
    #pragma unroll
    for (int k = 0; k < 8; ++k) {
        float fy = (float)(Y0 + qy + 8 * k);
        float sy = fmaf(id_, fx, fmaf(ie, fy, if_));
        float y0f = floorf(sy);
        int y0 = (int)y0f;
        int y1 = y0 + 1;
        float wy = sy - y0f;
        wy0[k] = ((y0 >= 0) & (y0 < IMH)) ? (1.f - wy) : 0.f;
        wy1[k] = ((y1 >= 0) & (y1 < IMH)) ? wy : 0.f;
        // clamp is monotone -> staged window [rlo,rhi] contains both rows
        int a0 = (clampi(y0, 0, IMH - 1) - rlo) * XW + px;   // < 3816 < 2^16
        int a1 = (clampi(y1, 0, IMH - 1) - rlo) * XW + px;
        a01[k] = a0 | (a1 << 16);
    }

    float* obase = out + (size_t)b * CH * HW + (Y0 + qy) * IMW + X0 + dx;

    #define SAMPLE(ch_, buf_) {                                               \
        const float* lp = (const float*)(buf_);                               \
        _Pragma("unroll")                                                     \
        for (int k = 0; k < 8; ++k) {                                         \
            int a0 = a01[k] & 0xffff;                                         \
            int a1 = a01[k] >> 16;                                            \
            float l00 = lp[a0], l01 = lp[a0 + 1];   /* ds_read2_b32 */        \
            float l10 = lp[a1], l11 = lp[a1 + 1];                             \
            float v = (l00 * wl + l01 * wh) * wy0[k]                          \
                    + (l10 * wl + l11 * wh) * wy1[k];                         \
            __builtin_nontemporal_store(v, obase + (ch_) * HW + 8 * k * IMW); \
        }                                                                     \
    }

    // ---- double-buffered channel pipeline: stage(ch+1) latency hides
    //      under sample(ch)'s LDS reads + stores; 3 barriers total ----
    __syncthreads();          // drains stage0 -> A ready
    STAGE(1, ldsB);           // in flight during SAMPLE(0)
    SAMPLE(0, ldsA);
    __syncthreads();          // drains stage1 -> B ready; A reads done
    STAGE(2, ldsA);           // in flight during SAMPLE(1)
    SAMPLE(1, ldsB);
    __syncthreads();          // drains stage2 -> A ready
    SAMPLE(2, ldsA);

    #undef STAGE
    #undef SAMPLE
}

extern "C" void kernel_launch(void* const* d_in, const int* in_sizes, int n_in,
                              void* d_out, int out_size, void* d_ws, size_t ws_size,
                              hipStream_t stream) {
    const float* img = (const float*)d_in[0];
    const float* rnd = (const float*)d_in[1];
    float* out = (float*)d_out;
    (void)d_ws; (void)ws_size;

    hipLaunchKernelGGL(TCR_52536039964687_warp, dim3(BATCH * 32), dim3(256),
                       0, stream, img, rnd, out);
}